// Round 15
// baseline (50.402 us; speedup 1.0000x reference)
//
#include <hip/hip_runtime.h>

typedef unsigned short u16;
typedef __attribute__((ext_vector_type(8))) __bf16 bf16x8;
typedef __attribute__((ext_vector_type(4))) float f32x4;

#define GLOAD_LDS16(g, l)                                                                     \
  __builtin_amdgcn_global_load_lds((const __attribute__((address_space(1))) unsigned int*)(g), \
                                   (__attribute__((address_space(3))) unsigned int*)(l), 16, 0, 0)

static __device__ __forceinline__ u16 f2bf(float f) {
  unsigned int u = __float_as_uint(f);
  u += 0x7fffu + ((u >> 16) & 1u);   // round-to-nearest-even
  return (u16)(u >> 16);
}

// Problem constants
#define BATCH 32
#define NN 1024
#define MM 512

// sX swizzle (R10-proven at b128): 2 lanes/chunk per 16-lane beat on both
// write (c consecutive per lane) and read (rb consecutive) sides = free.
static __device__ __forceinline__ int swz(int r) { return ((r >> 1) ^ ((r & 1) << 2)) & 7; }

// ---- kernel 1: pre-swizzled E|O matrix G[jt(8)][s(16)][row(64)][64] ----
// Row (jt,s,row): physical chunk pc holds data chunk dc = pc ^ (row&7):
//   dc<4 : E, k = 2*(s*32 + dc*8 + sub);  dc>=4: O, k = 2*(s*32+(dc-4)*8+sub)+1
__global__ void fill_g(u16* __restrict__ G) {
  int idx = blockIdx.x * 256 + threadIdx.x;  // 8*16*64*64 = 524288
  int jt  = idx >> 16;
  int s   = (idx >> 12) & 15;
  int row = (idx >> 6) & 63;
  int pc  = (idx >> 3) & 7;
  int sub = idx & 7;
  int dc = pc ^ (row & 7);
  int j = jt * 64 + row;
  int k;
  if (dc < 4) k = 2 * (s * 32 + dc * 8 + sub);
  else        k = 2 * (s * 32 + (dc - 4) * 8 + sub) + 1;
  float v;
  if (k == 0) {
    v = 0.03125f;  // 1/sqrt(1024)
  } else {
    int ph = (k * (2 * j + 1)) & 4095;
    v = 0.04419417382415922f * cosf((float)ph * 1.5339807878856412e-3f);
  }
  G[idx] = f2bf(v);
}

// ---- kernel 2: fused folded GEMM, depth-2 A+X pipeline, 32 KiB LDS ----
// out[j] = (E.Xe + O.Xo)[j], out[1023-j] = (E.Xe - O.Xo)[j].
// Block 256 thr / 4 waves (2wm x 2wn), tile 64jh x 64c; wave 32jh x 32c (E+O).
// LDS: sA[3][64*64] 24K (3-buf rotation => A issued 2 steps ahead) + sX 8K = 32K
// -> 4-5 blocks/CU resident.  Step s:
//   WRITE_X(s) [reg-wait on X(s), loaded at s-2]; vmcnt(18)+lgkm(0) [drains A(s);
//   A(s+1)+X(s+1)=18 ride across]; b1; ISSUE_A(s+2)->sA[(s+2)%3]; LOAD_X(s+2);
//   frag reads (sA[s%3], sX); 16 MFMA; b2.
// X staging: lane owns c = t&63, kq = t>>6 (k = kq*16..+16): 16 dword loads
// (64 lanes x 4B consecutive-c = 256B/instr), 2x bf16x8 LDS writes (E: chunk
// kq^swz(c); O: (4+kq)^swz(c)) -- b128, 2-way max = free.
// Gates: s<15: vmcnt(18); s==15: vmcnt(0) (already drained).
__global__ __launch_bounds__(256, 4) void gemm_idct(const u16* __restrict__ G,
                                                    const float* __restrict__ X,
                                                    float* __restrict__ C) {
  __shared__ __align__(16) u16 sA[3][4096];  // [buf][64 row][64]
  __shared__ __align__(16) u16 sX[4096];     // [64 c-row][64] (E chunks 0-3 | O 4-7)
  // --- XCD decode: 8 jt-sharers of each (ct,b) X-panel share wg&7 ---
  const int wg    = blockIdx.x;
  const int xcd   = wg & 7;
  const int local = wg >> 3;                  // 0..255
  const int jt    = local & 7;                // jh tile (64 rows)
  const int pg    = xcd * 32 + (local >> 3);  // 0..255
  const int ct    = pg & 7;                   // c tile (64 cols)
  const int b     = pg >> 3;                  // batch

  const int t = threadIdx.x;
  const int wave = t >> 6, lane = t & 63;
  const int wm = wave >> 1, wn = wave & 1;
  const int lhi = lane >> 4, llo = lane & 15;

  // --- A staging: 2 calls x 4KB; source linear (pre-swizzled at fill) ---
  const u16* gA = G + (size_t)jt * 65536 + t * 8;
#define ISSUE_A(buf, s)                                                        \
  do {                                                                         \
    GLOAD_LDS16(gA + (s) * 4096,        &sA[buf][t * 8]);                      \
    GLOAD_LDS16(gA + (s) * 4096 + 2048, &sA[buf][2048 + t * 8]);               \
  } while (0)

  // --- X: lane owns c = t&63, k-quarter kq = t>>6 (16 k per step) ---
  const int cx = t & 63;
  const int kq = t >> 6;
  const float* gX = X + ((size_t)b * NN + kq * 16) * MM + ct * 64 + cx;

#define LOAD_X(s, XR)                                                          \
  do {                                                                         \
    const float* p = gX + (size_t)(s) * 64 * MM;                               \
    _Pragma("unroll") for (int i = 0; i < 16; ++i)                             \
      XR[i] = p[(size_t)i * MM];                                               \
  } while (0)

  // E: k=kq*16+2i -> p-local chunk = kq; O analog at 4+kq.
#define WRITE_X(XR)                                                            \
  do {                                                                         \
    const int f = swz(cx);                                                     \
    bf16x8 e, o;                                                               \
    _Pragma("unroll") for (int m = 0; m < 8; ++m) {                            \
      e[m] = (__bf16)XR[2 * m];                                                \
      o[m] = (__bf16)XR[2 * m + 1];                                            \
    }                                                                          \
    *(bf16x8*)&sX[cx * 64 + ((kq ^ f) << 3)] = e;                              \
    *(bf16x8*)&sX[cx * 64 + (((4 + kq) ^ f) << 3)] = o;                        \
  } while (0)

  f32x4 accE[2][2] = {};
  f32x4 accO[2][2] = {};
  float xrA[16], xrB[16];

#define STEP(s, XR)                                                            \
  do {                                                                         \
    WRITE_X(XR); /* reg-wait drains thru X(s) */                               \
    if ((s) < 15)                                                              \
      asm volatile("s_waitcnt vmcnt(18) lgkmcnt(0)" ::: "memory");             \
    else                                                                       \
      asm volatile("s_waitcnt vmcnt(0) lgkmcnt(0)" ::: "memory");              \
    __builtin_amdgcn_sched_barrier(0);                                         \
    __builtin_amdgcn_s_barrier(); /* b1: sA[s%3] + sX ready everywhere */      \
    __builtin_amdgcn_sched_barrier(0);                                         \
    if ((s) < 14) {                                                            \
      ISSUE_A((s + 2) % 3, (s) + 2);                                           \
      LOAD_X((s) + 2, XR);                                                     \
    }                                                                          \
    {                                                                          \
      const u16* lA = &sA[(s) % 3][0];                                         \
      bf16x8 fe[2], fo[2], fxe[2], fxo[2];                                     \
      _Pragma("unroll") for (int mf = 0; mf < 2; ++mf) {                       \
        const int ra = wm * 32 + mf * 16 + llo;                                \
        const int fa = ra & 7;                                                 \
        fe[mf] = *(const bf16x8*)&lA[ra * 64 + ((lhi ^ fa) << 3)];             \
        fo[mf] = *(const bf16x8*)&lA[ra * 64 + (((4 + lhi) ^ fa) << 3)];       \
      }                                                                        \
      _Pragma("unroll") for (int nf = 0; nf < 2; ++nf) {                       \
        const int rb = wn * 32 + nf * 16 + llo;                                \
        const int fb = swz(rb);                                                \
        fxe[nf] = *(const bf16x8*)&sX[rb * 64 + ((lhi ^ fb) << 3)];            \
        fxo[nf] = *(const bf16x8*)&sX[rb * 64 + (((4 + lhi) ^ fb) << 3)];      \
      }                                                                        \
      __builtin_amdgcn_s_setprio(1);                                           \
      _Pragma("unroll") for (int mf = 0; mf < 2; ++mf)                         \
        _Pragma("unroll") for (int nf = 0; nf < 2; ++nf)                       \
          accE[mf][nf] = __builtin_amdgcn_mfma_f32_16x16x32_bf16(              \
              fe[mf], fxe[nf], accE[mf][nf], 0, 0, 0);                         \
      _Pragma("unroll") for (int mf = 0; mf < 2; ++mf)                         \
        _Pragma("unroll") for (int nf = 0; nf < 2; ++nf)                       \
          accO[mf][nf] = __builtin_amdgcn_mfma_f32_16x16x32_bf16(              \
              fo[mf], fxo[nf], accO[mf][nf], 0, 0, 0);                         \
      __builtin_amdgcn_s_setprio(0);                                           \
    }                                                                          \
    __builtin_amdgcn_sched_barrier(0);                                         \
    __builtin_amdgcn_s_barrier(); /* b2: separates reads(s) from WRITE_X(s+1) */ \
    __builtin_amdgcn_sched_barrier(0);                                         \
  } while (0)

  // ---- prologue: X(0)->A, A(0)->buf0, X(1)->B, A(1)->buf1 ----
  // FIFO at STEP(0): X0(16) A0(2) X1(16) A1(2); WRITE_X reg-wait leaves 20;
  // gate vmcnt(18) drains A(0). Steady state from s=0.
  LOAD_X(0, xrA);
  ISSUE_A(0, 0);
  LOAD_X(1, xrB);
  ISSUE_A(1, 1);

#pragma unroll
  for (int ss = 0; ss < 8; ++ss) {
    STEP(2 * ss,     xrA);
    STEP(2 * ss + 1, xrB);
  }

  // ---- epilogue: out[j] = Ye+Yo, out[1023-j] = Ye-Yo ----
  // C/D layout (m89-verified): col = lane&15, row = (lane>>4)*4 + reg
  float* Cb = C + (size_t)b * NN * MM;
  const int cbase = ct * 64 + wn * 32 + llo;
#pragma unroll
  for (int mf = 0; mf < 2; ++mf)
#pragma unroll
    for (int nf = 0; nf < 2; ++nf) {
      const int jh0 = jt * 64 + wm * 32 + mf * 16 + lhi * 4;
      const int c   = cbase + nf * 16;
#pragma unroll
      for (int r = 0; r < 4; ++r) {
        const float ye = accE[mf][nf][r];
        const float yo = accO[mf][nf][r];
        const int j = jh0 + r;
        Cb[(size_t)j * MM + c]            = ye + yo;
        Cb[(size_t)(NN - 1 - j) * MM + c] = ye - yo;
      }
    }
#undef ISSUE_A
#undef LOAD_X
#undef WRITE_X
#undef STEP
}

extern "C" void kernel_launch(void* const* d_in, const int* in_sizes, int n_in,
                              void* d_out, int out_size, void* d_ws, size_t ws_size,
                              hipStream_t stream) {
  const float* x = (const float*)d_in[0];
  float* out = (float*)d_out;
  u16* G = (u16*)d_ws;  // 524288 u16 = 1 MiB

  fill_g<<<dim3(2048), dim3(256), 0, stream>>>(G);
  gemm_idct<<<dim3(2048), dim3(256), 0, stream>>>(G, x, out);
}

// Round 16
// 44.553 us; speedup vs baseline: 1.1313x; 1.1313x over previous
//
#include <hip/hip_runtime.h>

typedef unsigned short u16;
typedef __attribute__((ext_vector_type(8))) __bf16 bf16x8;
typedef __attribute__((ext_vector_type(4))) float f32x4;

#define GLOAD_LDS16(g, l)                                                                     \
  __builtin_amdgcn_global_load_lds((const __attribute__((address_space(1))) unsigned int*)(g), \
                                   (__attribute__((address_space(3))) unsigned int*)(l), 16, 0, 0)

static __device__ __forceinline__ u16 f2bf(float f) {
  unsigned int u = __float_as_uint(f);
  u += 0x7fffu + ((u >> 16) & 1u);   // round-to-nearest-even
  return (u16)(u >> 16);
}

// Problem constants
#define BATCH 32
#define NN 1024
#define MM 512

// X-side chunk swizzle (R10/R15-proven, 0 conflicts at b128): 2 lanes/chunk
// per 16-lane beat on both write and read sides = free (m136).
static __device__ __forceinline__ int swz(int r) { return ((r >> 1) ^ ((r & 1) << 2)) & 7; }

// ---- kernel 1: pre-swizzled E|O matrix G2[jt(4)][s(8)][row(128)][E 64|O 64] ----
// Per row: elems 0..63 = E half (8 chunks), 64..127 = O half. Physical chunk pc
// within a half holds data chunk dc = pc ^ (row&7) (R12-proven A swizzle):
//   p = s*64 + dc*8 + sub;  E: k = 2p;  O: k = 2p+1;  j = jt*128 + row.
__global__ void fill_g(u16* __restrict__ G) {
  int idx = blockIdx.x * 256 + threadIdx.x;  // 4*8*128*128 = 524288
  int jt   = idx >> 17;
  int s    = (idx >> 14) & 7;
  int row  = (idx >> 7) & 127;
  int rest = idx & 127;
  int eo   = rest >> 6;          // 0 = E, 1 = O
  int pc   = (rest >> 3) & 7;
  int sub  = rest & 7;
  int dc = pc ^ (row & 7);
  int p = s * 64 + dc * 8 + sub;
  int k = 2 * p + eo;
  int j = jt * 128 + row;
  float v;
  if (k == 0) {
    v = 0.03125f;  // 1/sqrt(1024)
  } else {
    int ph = (k * (2 * j + 1)) & 4095;
    v = 0.04419417382415922f * cosf((float)ph * 1.5339807878856412e-3f);
  }
  G[idx] = f2bf(v);
}

// ---- kernel 2: fused folded GEMM, 8-step cadence (BK=64 p = 128 k) ----
// out[j] = (E.Xe + O.Xo)[j], out[1023-j] = (E.Xe - O.Xo)[j].
// Block 256 thr / 4 waves (2wm x 2wn), tile 128jh x 64c; wave 64jh x 32c (E+O).
// LDS: sA[2][128 row][128] = 64K (dbuf; linear gload_lds from pre-swizzled G2)
//      sX[64 c][E 64|O 64] = 16K  -> 80K, 2 blocks/CU.
// Step s: WRITE_X(s) [compiler reg-wait on X(s) = youngest outstanding -> also
//   drains A(s), FIFO]; lgkmcnt(0); b1; if s<7: ISSUE_A(s+1)->sA[(s+1)&1] (8 calls),
//   LOAD_X(s+1) (32 dwords); 2 ks-subphases x {12 frag reads; 8 E-MFMA; 8 O-MFMA};
//   b2.  32 MFMA/wave/step, 8 steps — R8's proven cadence, transpose fused in.
__global__ __launch_bounds__(256, 2) void gemm_idct(const u16* __restrict__ G,
                                                    const float* __restrict__ X,
                                                    float* __restrict__ C) {
  __shared__ __align__(16) u16 sA[2][16384];  // [buf][128 row][128]
  __shared__ __align__(16) u16 sX[8192];      // [64 c][128] (E 8 chunks | O 8 chunks)
  // --- XCD decode: 4 jt-sharers of each (ct,b) X-panel share wg&7 ---
  const int wg    = blockIdx.x;
  const int xcd   = wg & 7;
  const int local = wg >> 3;                  // 0..127
  const int jt    = local & 3;                // jh tile (128 rows)
  const int pg    = xcd * 32 + (local >> 2);  // 0..255
  const int ct    = pg & 7;                   // c tile (64 cols)
  const int b     = pg >> 3;                  // batch

  const int t = threadIdx.x;
  const int wave = t >> 6, lane = t & 63;
  const int wm = wave >> 1, wn = wave & 1;
  const int lhi = lane >> 4, llo = lane & 15;

  // --- A staging: 8 calls x 4KB per step; source linear (pre-swizzled fill) ---
  const u16* gA = G + (size_t)jt * 131072 + t * 8;
#define ISSUE_A(buf, s)                                                        \
  do {                                                                         \
    _Pragma("unroll") for (int cl = 0; cl < 8; ++cl)                           \
      GLOAD_LDS16(gA + (s) * 16384 + cl * 2048, &sA[buf][cl * 2048 + t * 8]);  \
  } while (0)

  // --- X: lane owns c = t&63, k-quarter kq = t>>6 (32 k per step) ---
  const int cx = t & 63;
  const int kq = t >> 6;
  const float* gX = X + ((size_t)b * NN + kq * 32) * MM + ct * 64 + cx;

  float xr[32];
#define LOAD_X(s)                                                              \
  do {                                                                         \
    const float* p = gX + (size_t)(s) * 128 * MM;                              \
    _Pragma("unroll") for (int i = 0; i < 32; ++i)                             \
      xr[i] = p[(size_t)i * MM];                                               \
  } while (0)

  // k = kq*32 + m (m 0..31); p-local = kq*16 + (m>>1); chunk h in {0,1}:
  // E chunk 2kq+h holds xr[16h + 2i], O chunk 2kq+h holds xr[16h + 2i + 1].
#define WRITE_X()                                                              \
  do {                                                                         \
    const int f = swz(cx);                                                     \
    _Pragma("unroll") for (int h = 0; h < 2; ++h) {                            \
      bf16x8 e, o;                                                             \
      _Pragma("unroll") for (int i = 0; i < 8; ++i) {                          \
        e[i] = (__bf16)xr[16 * h + 2 * i];                                     \
        o[i] = (__bf16)xr[16 * h + 2 * i + 1];                                 \
      }                                                                        \
      const int ch = (2 * kq + h) ^ f;                                         \
      *(bf16x8*)&sX[cx * 128 + ch * 8] = e;                                    \
      *(bf16x8*)&sX[cx * 128 + 64 + ch * 8] = o;                               \
    }                                                                          \
  } while (0)

  f32x4 accE[4][2] = {};
  f32x4 accO[4][2] = {};

#define STEP(s)                                                                \
  do {                                                                         \
    WRITE_X(); /* reg-wait drains X(s) and (FIFO) A(s) */                      \
    asm volatile("s_waitcnt lgkmcnt(0)" ::: "memory");                         \
    __builtin_amdgcn_sched_barrier(0);                                         \
    __builtin_amdgcn_s_barrier(); /* b1: sA[s&1] + sX ready everywhere */      \
    __builtin_amdgcn_sched_barrier(0);                                         \
    if ((s) < 7) {                                                             \
      ISSUE_A(((s) + 1) & 1, (s) + 1);                                         \
      LOAD_X((s) + 1);                                                         \
    }                                                                          \
    {                                                                          \
      const u16* lA = &sA[(s) & 1][0];                                         \
      _Pragma("unroll") for (int ks = 0; ks < 2; ++ks) {                       \
        bf16x8 fe[4], fo[4], fxe[2], fxo[2];                                   \
        _Pragma("unroll") for (int mf = 0; mf < 4; ++mf) {                     \
          const int ra = wm * 64 + mf * 16 + llo;                              \
          const int ca = ((ks * 4 + lhi) ^ (ra & 7)) << 3;                     \
          fe[mf] = *(const bf16x8*)&lA[ra * 128 + ca];                         \
          fo[mf] = *(const bf16x8*)&lA[ra * 128 + 64 + ca];                    \
        }                                                                      \
        _Pragma("unroll") for (int nf = 0; nf < 2; ++nf) {                     \
          const int rb = wn * 32 + nf * 16 + llo;                              \
          const int cb = ((ks * 4 + lhi) ^ swz(rb)) << 3;                      \
          fxe[nf] = *(const bf16x8*)&sX[rb * 128 + cb];                        \
          fxo[nf] = *(const bf16x8*)&sX[rb * 128 + 64 + cb];                   \
        }                                                                      \
        __builtin_amdgcn_s_setprio(1);                                         \
        _Pragma("unroll") for (int mf = 0; mf < 4; ++mf)                       \
          _Pragma("unroll") for (int nf = 0; nf < 2; ++nf)                     \
            accE[mf][nf] = __builtin_amdgcn_mfma_f32_16x16x32_bf16(            \
                fe[mf], fxe[nf], accE[mf][nf], 0, 0, 0);                       \
        _Pragma("unroll") for (int mf = 0; mf < 4; ++mf)                       \
          _Pragma("unroll") for (int nf = 0; nf < 2; ++nf)                     \
            accO[mf][nf] = __builtin_amdgcn_mfma_f32_16x16x32_bf16(            \
                fo[mf], fxo[nf], accO[mf][nf], 0, 0, 0);                       \
        __builtin_amdgcn_s_setprio(0);                                         \
      }                                                                        \
    }                                                                          \
    __builtin_amdgcn_sched_barrier(0);                                         \
    __builtin_amdgcn_s_barrier(); /* b2: reads(s) precede WRITE_X(s+1) */      \
    __builtin_amdgcn_sched_barrier(0);                                         \
  } while (0)

  // ---- prologue ----
  ISSUE_A(0, 0);
  LOAD_X(0);

  STEP(0); STEP(1); STEP(2); STEP(3);
  STEP(4); STEP(5); STEP(6); STEP(7);

  // ---- epilogue: out[j] = Ye+Yo, out[1023-j] = Ye-Yo ----
  // C/D layout (m89-verified): col = lane&15, row = (lane>>4)*4 + reg
  float* Cb = C + (size_t)b * NN * MM;
  const int cbase = ct * 64 + wn * 32 + llo;
#pragma unroll
  for (int mf = 0; mf < 4; ++mf)
#pragma unroll
    for (int nf = 0; nf < 2; ++nf) {
      const int jh0 = jt * 128 + wm * 64 + mf * 16 + lhi * 4;
      const int c   = cbase + nf * 16;
#pragma unroll
      for (int r = 0; r < 4; ++r) {
        const float ye = accE[mf][nf][r];
        const float yo = accO[mf][nf][r];
        const int j = jh0 + r;
        Cb[(size_t)j * MM + c]            = ye + yo;
        Cb[(size_t)(NN - 1 - j) * MM + c] = ye - yo;
      }
    }
#undef ISSUE_A
#undef LOAD_X
#undef WRITE_X
#undef STEP
}

extern "C" void kernel_launch(void* const* d_in, const int* in_sizes, int n_in,
                              void* d_out, int out_size, void* d_ws, size_t ws_size,
                              hipStream_t stream) {
  const float* x = (const float*)d_in[0];
  float* out = (float*)d_out;
  u16* G = (u16*)d_ws;  // 524288 u16 = 1 MiB

  fill_g<<<dim3(2048), dim3(256), 0, stream>>>(G);
  gemm_idct<<<dim3(1024), dim3(256), 0, stream>>>(G, x, out);
}